// Round 6
// baseline (538.465 us; speedup 1.0000x reference)
//
#include <hip/hip_runtime.h>
#include <hip/hip_fp16.h>

typedef _Float16 half8 __attribute__((ext_vector_type(8)));
typedef _Float16 half4v __attribute__((ext_vector_type(4)));
typedef float floatx4 __attribute__((ext_vector_type(4)));

// ---------------- async global->LDS (16B per lane) ----------------
__device__ __forceinline__ void load_lds16(const void* g, void* l) {
    __builtin_amdgcn_global_load_lds(
        (const __attribute__((address_space(1))) void*)g,
        (__attribute__((address_space(3))) void*)l,
        16, 0, 0);
}

// Stage one 128x64 fp16 half-tile (16 KiB) into LDS. LDS dest is linear
// (global_load_lds requirement); the SOURCE slot is XOR-pre-swizzled
// (slot ^= row&7) so a swizzled reader sees natural data (Guideline 21).
__device__ __forceinline__ void stage_half(const _Float16* g, long ld, _Float16* dst) {
    const int t = threadIdx.x;  // 512 threads x 2 chunks x 16B
#pragma unroll
    for (int j = 0; j < 2; ++j) {
        const int c = j * 512 + t;             // 0..1023
        const int row = c >> 3;                // 0..127
        const int slot = (c & 7) ^ (row & 7);  // pre-swizzled source slot
        load_lds16(g + (long)row * ld + slot * 8, dst + c * 8);
    }
}

// ---------------- 256x256 gemm_bt core, ONE barrier per K-tile ----------------
// C[m,n] += sum_k A[m,k]*B[n,k]. BM=BN=256, BK=64, 512 threads = 8 waves
// (2M x 4N); per-wave 128x64 = 8x4 frags of 16x16, mfma 16x16x32 f16.
// LDS: 2 tile-buffers x (A 32K + B 32K) = 128 KiB.
// Loop invariant at tile t entry barrier: buf[t&1] staged & drained,
// all waves done reading buf[(t-1)&1]. Body: issue STAGE(t+1 -> buf^1),
// 24 ds_reads + 64 MFMA compiler-scheduled (counted lgkmcnt), setprio(1)
// through the MFMA burst (T5: favors MFMA-ready waves while others read),
// vmcnt(0) drain placed MID-burst (residual latency covered by last quad).
__device__ __forceinline__ void gemm256_core(const _Float16* A, long lda,
                                             const _Float16* B, long ldb,
                                             int K, floatx4 acc[8][4],
                                             _Float16* lds) {
    const int lane = threadIdx.x & 63;
    const int w    = threadIdx.x >> 6;   // 0..7
    const int wr   = w >> 2;             // 0..1
    const int wc   = w & 3;              // 0..3
    const int rsel = lane & 15, gsel = lane >> 4;
    const int NT = K >> 6;

#define STAGE(BUF, KT)                                                             \
    stage_half(A + (KT) * 64, lda, lds + (BUF) * 32768);                           \
    stage_half(A + (long)128 * lda + (KT) * 64, lda, lds + (BUF) * 32768 + 8192);  \
    stage_half(B + (KT) * 64, ldb, lds + (BUF) * 32768 + 16384);                   \
    stage_half(B + (long)128 * ldb + (KT) * 64, ldb, lds + (BUF) * 32768 + 24576);
#define READ_A(dst, AH, MH)                                                        \
    _Pragma("unroll") for (int mi = 0; mi < 4; ++mi) {                             \
        const int r = ((MH) * 4 + mi) * 16 + rsel;                                 \
        dst[mi][0] = *(const half8*)&(AH)[r * 64 + ((gsel ^ (r & 7)) << 3)];       \
        dst[mi][1] = *(const half8*)&(AH)[r * 64 + (((4 + gsel) ^ (r & 7)) << 3)]; \
    }
#define READ_B(dst, BH, NH)                                                        \
    _Pragma("unroll") for (int ni = 0; ni < 2; ++ni) {                             \
        const int rn = (wc & 1) * 64 + ((NH) * 2 + ni) * 16 + rsel;                \
        dst[ni][0] = *(const half8*)&(BH)[rn * 64 + ((gsel ^ (rn & 7)) << 3)];     \
        dst[ni][1] = *(const half8*)&(BH)[rn * 64 + (((4 + gsel) ^ (rn & 7)) << 3)]; \
    }
#define MFMA_Q(MH, NH, A_, B_)                                                     \
    _Pragma("unroll") for (int mi = 0; mi < 4; ++mi)                               \
    _Pragma("unroll") for (int ni = 0; ni < 2; ++ni) {                             \
        acc[(MH) * 4 + mi][(NH) * 2 + ni] = __builtin_amdgcn_mfma_f32_16x16x32_f16( \
            A_[mi][0], B_[ni][0], acc[(MH) * 4 + mi][(NH) * 2 + ni], 0, 0, 0);     \
        acc[(MH) * 4 + mi][(NH) * 2 + ni] = __builtin_amdgcn_mfma_f32_16x16x32_f16( \
            A_[mi][1], B_[ni][1], acc[(MH) * 4 + mi][(NH) * 2 + ni], 0, 0, 0);     \
    }

    half8 a_lo[4][2], a_hi[4][2], b_lo[2][2], b_hi[2][2];

    // prologue: stage tile 0, drain, rendezvous
    STAGE(0, 0);
    asm volatile("s_waitcnt vmcnt(0)" ::: "memory");
    __builtin_amdgcn_s_barrier();
    __builtin_amdgcn_sched_barrier(0);

#pragma unroll 1
    for (int t = 0; t < NT; ++t) {
        const int buf = t & 1;
        if (t + 1 < NT) { STAGE(buf ^ 1, t + 1); }
        const _Float16* Ah = lds + buf * 32768 + wr * 8192;
        const _Float16* Bh = lds + buf * 32768 + 16384 + (wc >> 1) * 8192;
        READ_A(a_lo, Ah, 0);
        READ_B(b_lo, Bh, 0);
        READ_A(a_hi, Ah, 1);
        READ_B(b_hi, Bh, 1);
        __builtin_amdgcn_s_setprio(1);
        MFMA_Q(0, 0, a_lo, b_lo);
        MFMA_Q(1, 0, a_hi, b_lo);
        MFMA_Q(0, 1, a_lo, b_hi);
        // own stage loads (issued a full tile ago): drain mid-burst so any
        // residual latency is covered by the last quadrant's MFMAs
        asm volatile("s_waitcnt vmcnt(0)" ::: "memory");
        MFMA_Q(1, 1, a_hi, b_hi);
        __builtin_amdgcn_s_setprio(0);
        __builtin_amdgcn_s_barrier();
        __builtin_amdgcn_sched_barrier(0);
    }
#undef STAGE
#undef READ_A
#undef READ_B
#undef MFMA_Q
}

__device__ __forceinline__ void zero_acc8(floatx4 acc[8][4]) {
    const floatx4 z = {0.f, 0.f, 0.f, 0.f};
#pragma unroll
    for (int m = 0; m < 8; ++m)
#pragma unroll
        for (int n = 0; n < 4; ++n) acc[m][n] = z;
}

// ---------------- kernels ----------------

// merged prep: blocks [0,16384) build X fp16 [16384][1024] from concat;
// blocks [16384,20480) convert Wq,Wk,Wv,Wf fp32 -> Wh fp16 [4][1024][1024]
__global__ __launch_bounds__(256) void prep_kernel(const float* e1, const float* e2,
                                                   const float* e3, const float* Wq,
                                                   const float* Wk, const float* Wv,
                                                   const float* Wf, _Float16* X,
                                                   _Float16* Wdst) {
    const int bid = blockIdx.x;
    if (bid < 16384) {
        long i = ((long)bid * 256 + threadIdx.x) * 4;  // < 16384*1024
        int m = (int)(i >> 10);
        int c = (int)(i & 1023);
        const float* src;
        if (c < 256)      src = e1 + (long)m * 256 + c;
        else if (c < 512) src = e2 + (long)m * 256 + (c - 256);
        else              src = e3 + (long)m * 512 + (c - 512);
        float4 f = *(const float4*)src;
        half4v h;
        h[0] = (_Float16)f.x; h[1] = (_Float16)f.y;
        h[2] = (_Float16)f.z; h[3] = (_Float16)f.w;
        *(half4v*)&X[i] = h;
    } else {
        long i = ((long)(bid - 16384) * 256 + threadIdx.x) * 4;  // < 4*1048576
        int which = (int)(i >> 20);
        long off = i & 1048575;
        const float* w = which == 0 ? Wq : which == 1 ? Wk : which == 2 ? Wv : Wf;
        float4 f = *(const float4*)(w + off);
        half4v h;
        h[0] = (_Float16)f.x; h[1] = (_Float16)f.y;
        h[2] = (_Float16)f.z; h[3] = (_Float16)f.w;
        *(half4v*)&Wdst[i] = h;
    }
}

// QKV projection: z=0 -> q, z=1 -> k (row-major [16384][1024]),
// z=2 -> v written TRANSPOSED as vT [1024][16384] via LDS transpose
// (direct scatter was 8B/lane at 32KB stride -> write amplification).
__global__ __launch_bounds__(512, 2) void qkv_kernel(const _Float16* X, const _Float16* W,
                                                     const float* bq, const float* bk,
                                                     const float* bv, _Float16* q,
                                                     _Float16* k, _Float16* vT) {
    extern __shared__ _Float16 lds[];
    const int m0 = blockIdx.x * 256;
    const int n0 = blockIdx.y * 256;
    const int z  = blockIdx.z;
    floatx4 acc[8][4];
    zero_acc8(acc);
    gemm256_core(X + (long)m0 * 1024, 1024,
                 W + (long)z * 1048576 + (long)n0 * 1024, 1024, 1024, acc, lds);

    const float* bias = (z == 0) ? bq : (z == 1) ? bk : bv;
    const int lane = threadIdx.x & 63;
    const int w = threadIdx.x >> 6;
    const int wr = w >> 2, wc = w & 3;
    const int rsel = lane & 15, gsel = lane >> 4;

    if (z == 2) {
        // ---- bias + fp16 cvt into LDS [c][r], XOR-swizzled r to spread banks
        const int rb = wr * 128 + gsel * 4;   // + mI*16 (+j)
        const int cb = wc * 64 + rsel;        // + nI*16
#pragma unroll
        for (int mI = 0; mI < 8; ++mI) {
#pragma unroll
            for (int nI = 0; nI < 4; ++nI) {
                const int c = cb + nI * 16;
                const int r = rb + mI * 16;
                const float bb = bias[n0 + c];
                half4v vv;
#pragma unroll
                for (int j = 0; j < 4; ++j) vv[j] = (_Float16)(acc[mI][nI][j] + bb);
                *(half4v*)&lds[c * 256 + (r ^ ((c & 7) << 3))] = vv;
            }
        }
        __syncthreads();
        // ---- write vT rows: 256 cols x 32 chunks of 16B, contiguous in m
#pragma unroll
        for (int it = 0; it < 16; ++it) {
            const int idx = it * 512 + threadIdx.x;  // 0..8191
            const int c = idx >> 5;                  // 0..255
            const int mc = idx & 31;                 // 16B chunk
            half8 v = *(const half8*)&lds[c * 256 + ((mc * 8) ^ ((c & 7) << 3))];
            *(half8*)&vT[(long)(n0 + c) * 16384 + m0 + mc * 8] = v;
        }
    } else {
        _Float16* dst = (z == 0) ? q : k;
        const int r0 = m0 + wr * 128 + gsel * 4;
        const int c0 = n0 + wc * 64 + rsel;
#pragma unroll
        for (int mI = 0; mI < 8; ++mI) {
#pragma unroll
            for (int nI = 0; nI < 4; ++nI) {
                const int r = r0 + mI * 16;
                const int c = c0 + nI * 16;
                const float bb = bias[c];
#pragma unroll
                for (int j = 0; j < 4; ++j)
                    dst[(long)(r + j) * 1024 + c] = (_Float16)(acc[mI][nI][j] + bb);
            }
        }
    }
}

// scores[b] = q[b] @ k[b]^T  (fp32 out, chunk-local batch index bz)
__global__ __launch_bounds__(512, 2) void scores_kernel(const _Float16* qh,
                                                        const _Float16* kh, float* scores,
                                                        int b0) {
    extern __shared__ _Float16 lds[];
    const int m0 = blockIdx.x * 256;
    const int n0 = blockIdx.y * 256;
    const int bz = blockIdx.z;
    const int batch = b0 + bz;
    float* C = scores + (long)bz * 2048 * 2048;
    floatx4 acc[8][4];
    zero_acc8(acc);
    gemm256_core(qh + ((long)batch * 2048 + m0) * 1024, 1024,
                 kh + ((long)batch * 2048 + n0) * 1024, 1024, 1024, acc, lds);

    const int lane = threadIdx.x & 63;
    const int w = threadIdx.x >> 6;
    const int wr = w >> 2, wc = w & 3;
    const int r0 = m0 + wr * 128 + (lane >> 4) * 4;
    const int c0 = n0 + wc * 64 + (lane & 15);
#pragma unroll
    for (int m = 0; m < 8; ++m) {
#pragma unroll
        for (int n = 0; n < 4; ++n) {
            const int r = r0 + m * 16;
            const int c = c0 + n * 16;
#pragma unroll
            for (int j = 0; j < 4; ++j)
                C[(long)(r + j) * 2048 + c] = acc[m][n][j];
        }
    }
}

// row softmax over 2048 fp32 scores -> fp16 probs. one block per row.
__global__ __launch_bounds__(256) void softmax_kernel(const float* scores,
                                                      _Float16* probs, int b0) {
    const int row = blockIdx.x;
    const int bz  = blockIdx.y;
    const float* s = scores + ((long)bz * 2048 + row) * 2048;
    _Float16* p = probs + ((long)(b0 + bz) * 2048 + row) * 2048;
    const int t = threadIdx.x;

    float4 x0 = ((const float4*)s)[t * 2];
    float4 x1 = ((const float4*)s)[t * 2 + 1];
    float v[8] = {x0.x, x0.y, x0.z, x0.w, x1.x, x1.y, x1.z, x1.w};

    float mx = v[0];
#pragma unroll
    for (int j = 1; j < 8; ++j) mx = fmaxf(mx, v[j]);
#pragma unroll
    for (int d = 1; d < 64; d <<= 1) mx = fmaxf(mx, __shfl_xor(mx, d));
    __shared__ float smax[4];
    __shared__ float ssum[4];
    if ((t & 63) == 0) smax[t >> 6] = mx;
    __syncthreads();
    mx = fmaxf(fmaxf(smax[0], smax[1]), fmaxf(smax[2], smax[3]));

    float e[8];
    float sum = 0.f;
#pragma unroll
    for (int j = 0; j < 8; ++j) {
        e[j] = __expf(v[j] - mx);
        sum += e[j];
    }
#pragma unroll
    for (int d = 1; d < 64; d <<= 1) sum += __shfl_xor(sum, d);
    if ((t & 63) == 0) ssum[t >> 6] = sum;
    __syncthreads();
    sum = ssum[0] + ssum[1] + ssum[2] + ssum[3];
    const float inv = 1.0f / sum;

    half8 o;
#pragma unroll
    for (int j = 0; j < 8; ++j) o[j] = (_Float16)(e[j] * inv);
    *(half8*)&p[t * 8] = o;
}

// weighted[b] = probs[b] @ v[b] via vT (gemm_bt form). fp16 out [16384][1024].
__global__ __launch_bounds__(512, 2) void pv_kernel(const _Float16* probs,
                                                    const _Float16* vT, _Float16* wt) {
    extern __shared__ _Float16 lds[];
    const int m0 = blockIdx.x * 256;
    const int n0 = blockIdx.y * 256;
    const int batch = blockIdx.z;
    floatx4 acc[8][4];
    zero_acc8(acc);
    gemm256_core(probs + ((long)batch * 2048 + m0) * 2048, 2048,
                 vT + (long)n0 * 16384 + (long)batch * 2048, 16384, 2048, acc, lds);

    const int lane = threadIdx.x & 63;
    const int w = threadIdx.x >> 6;
    const int wr = w >> 2, wc = w & 3;
    const int r0 = wr * 128 + (lane >> 4) * 4;
    const int c0 = n0 + wc * 64 + (lane & 15);
#pragma unroll
    for (int m = 0; m < 8; ++m) {
#pragma unroll
        for (int n = 0; n < 4; ++n) {
            const int r = r0 + m * 16;
            const int c = c0 + n * 16;
#pragma unroll
            for (int j = 0; j < 4; ++j)
                wt[((long)batch * 2048 + m0 + r + j) * 1024 + c] =
                    (_Float16)acc[m][n][j];
        }
    }
}

// out = leakyrelu(weighted @ Wf^T + bf), fp32 out.
__global__ __launch_bounds__(512, 2) void out_kernel(const _Float16* wt, const _Float16* Wf,
                                                     const float* bf_, float* out) {
    extern __shared__ _Float16 lds[];
    const int m0 = blockIdx.x * 256;
    const int n0 = blockIdx.y * 256;
    floatx4 acc[8][4];
    zero_acc8(acc);
    gemm256_core(wt + (long)m0 * 1024, 1024, Wf + (long)n0 * 1024, 1024, 1024, acc, lds);

    const int lane = threadIdx.x & 63;
    const int w = threadIdx.x >> 6;
    const int wr = w >> 2, wc = w & 3;
    const int r0 = m0 + wr * 128 + (lane >> 4) * 4;
    const int c0 = n0 + wc * 64 + (lane & 15);
#pragma unroll
    for (int m = 0; m < 8; ++m) {
#pragma unroll
        for (int n = 0; n < 4; ++n) {
            const int r = r0 + m * 16;
            const int c = c0 + n * 16;
            const float bb = bf_[c];
#pragma unroll
            for (int j = 0; j < 4; ++j) {
                float y = acc[m][n][j] + bb;
                y = (y >= 0.f) ? y : 0.2f * y;
                out[(long)(r + j) * 1024 + c] = y;
            }
        }
    }
}

// ---------------- launcher ----------------
extern "C" void kernel_launch(void* const* d_in, const int* in_sizes, int n_in,
                              void* d_out, int out_size, void* d_ws, size_t ws_size,
                              hipStream_t stream) {
    const float* e1 = (const float*)d_in[0];
    const float* e2 = (const float*)d_in[1];
    const float* e3 = (const float*)d_in[2];
    const float* Wq = (const float*)d_in[3];
    const float* bq = (const float*)d_in[4];
    const float* Wk = (const float*)d_in[5];
    const float* bk = (const float*)d_in[6];
    const float* Wv = (const float*)d_in[7];
    const float* bv = (const float*)d_in[8];
    const float* Wf = (const float*)d_in[9];
    const float* bf_ = (const float*)d_in[10];
    float* out = (float*)d_out;

    // raise dynamic-LDS cap to 128 KiB (idempotent; not a stream op)
    const int LDS_BYTES = 131072;
    (void)hipFuncSetAttribute((const void*)qkv_kernel,
                              hipFuncAttributeMaxDynamicSharedMemorySize, LDS_BYTES);
    (void)hipFuncSetAttribute((const void*)scores_kernel,
                              hipFuncAttributeMaxDynamicSharedMemorySize, LDS_BYTES);
    (void)hipFuncSetAttribute((const void*)pv_kernel,
                              hipFuncAttributeMaxDynamicSharedMemorySize, LDS_BYTES);
    (void)hipFuncSetAttribute((const void*)out_kernel,
                              hipFuncAttributeMaxDynamicSharedMemorySize, LDS_BYTES);

    char* ws = (char*)d_ws;
    const size_t MB = 1024 * 1024;
    _Float16* Xh    = (_Float16*)(ws + 0);        // 32 MiB
    _Float16* Wh    = (_Float16*)(ws + 32 * MB);  // 8 MiB [4][1024][1024]
    _Float16* qh    = (_Float16*)(ws + 40 * MB);  // 32 MiB
    _Float16* kh    = (_Float16*)(ws + 72 * MB);  // 32 MiB
    _Float16* vT    = (_Float16*)(ws + 104 * MB); // 32 MiB [1024][16384]
    _Float16* wt    = (_Float16*)(ws + 136 * MB); // 32 MiB
    _Float16* probs = (_Float16*)(ws + 168 * MB); // 64 MiB [8][2048][2048]
    float* scores   = (float*)(ws + 232 * MB);    // NB * 16 MiB scratch

    long nb_max = ((long)ws_size - 232 * (long)MB) / (16 * (long)MB);
    int NB = (int)(nb_max < 1 ? 1 : (nb_max > 8 ? 8 : nb_max));

    prep_kernel<<<20480, 256, 0, stream>>>(e1, e2, e3, Wq, Wk, Wv, Wf, Xh, Wh);
    qkv_kernel<<<dim3(64, 4, 3), 512, LDS_BYTES, stream>>>(Xh, Wh, bq, bk, bv, qh, kh, vT);
    for (int b0 = 0; b0 < 8; b0 += NB) {
        int nb = 8 - b0 < NB ? 8 - b0 : NB;
        scores_kernel<<<dim3(8, 8, nb), 512, LDS_BYTES, stream>>>(qh, kh, scores, b0);
        softmax_kernel<<<dim3(2048, nb), 256, 0, stream>>>(scores, probs, b0);
    }
    pv_kernel<<<dim3(8, 4, 8), 512, LDS_BYTES, stream>>>(probs, vT, wt);
    out_kernel<<<dim3(64, 4), 512, LDS_BYTES, stream>>>(wt, Wh + 3 * 1048576, bf_, out);
}

// Round 7
// 472.306 us; speedup vs baseline: 1.1401x; 1.1401x over previous
//
#include <hip/hip_runtime.h>
#include <hip/hip_fp16.h>

typedef _Float16 half8 __attribute__((ext_vector_type(8)));
typedef _Float16 half4v __attribute__((ext_vector_type(4)));
typedef float floatx4 __attribute__((ext_vector_type(4)));

// ---------------- async global->LDS (16B per lane) ----------------
__device__ __forceinline__ void load_lds16(const void* g, void* l) {
    __builtin_amdgcn_global_load_lds(
        (const __attribute__((address_space(1))) void*)g,
        (__attribute__((address_space(3))) void*)l,
        16, 0, 0);
}

// Stage one 128x64 fp16 half-tile (16 KiB) into LDS. LDS dest is linear
// (global_load_lds requirement); the SOURCE slot is XOR-pre-swizzled
// (slot ^= row&7) so a swizzled reader sees natural data (Guideline 21).
__device__ __forceinline__ void stage_half(const _Float16* g, long ld, _Float16* dst) {
    const int t = threadIdx.x;  // 512 threads x 2 chunks x 16B
#pragma unroll
    for (int j = 0; j < 2; ++j) {
        const int c = j * 512 + t;             // 0..1023
        const int row = c >> 3;                // 0..127
        const int slot = (c & 7) ^ (row & 7);  // pre-swizzled source slot
        load_lds16(g + (long)row * ld + slot * 8, dst + c * 8);
    }
}

// ---------------- 256x256 gemm_bt core, ONE barrier per K-tile ----------------
// C[m,n] += sum_k A[m,k]*B[n,k]. BM=BN=256, BK=64, 512 threads = 8 waves
// (2M x 4N); per-wave 128x64 = 8x4 frags of 16x16, mfma 16x16x32 f16.
// LDS: 2 tile-buffers x (A 32K + B 32K) = 128 KiB.
// R5 post-mortem: with no pins the compiler serialized each tile into
// {all 24 ds_reads} then {64 MFMA} (5550cy/tile = 2048+2483+sync).
// This version forces quadrant-ahead overlap with COUNTED lgkmcnt:
// reads issued in pinned FIFO order (12 | 8 | 4), then lgkmcnt(12)->Q00,
// lgkmcnt(4)->Q10, lgkmcnt(0)->Q01+Q11 -- so 8-12 reads are always in
// flight under the previous 16-MFMA cluster. 3 counted pins per tile.
// NO setprio (m190/R6: hurts lockstep GEMM). Drain vmcnt(0) at tile end.
__device__ __forceinline__ void gemm256_core(const _Float16* A, long lda,
                                             const _Float16* B, long ldb,
                                             int K, floatx4 acc[8][4],
                                             _Float16* lds) {
    const int lane = threadIdx.x & 63;
    const int w    = threadIdx.x >> 6;   // 0..7
    const int wr   = w >> 2;             // 0..1
    const int wc   = w & 3;              // 0..3
    const int rsel = lane & 15, gsel = lane >> 4;
    const int NT = K >> 6;

#define STAGE(BUF, KT)                                                             \
    stage_half(A + (KT) * 64, lda, lds + (BUF) * 32768);                           \
    stage_half(A + (long)128 * lda + (KT) * 64, lda, lds + (BUF) * 32768 + 8192);  \
    stage_half(B + (KT) * 64, ldb, lds + (BUF) * 32768 + 16384);                   \
    stage_half(B + (long)128 * ldb + (KT) * 64, ldb, lds + (BUF) * 32768 + 24576);
#define READ_A(dst, AH, MH)                                                        \
    _Pragma("unroll") for (int mi = 0; mi < 4; ++mi) {                             \
        const int r = ((MH) * 4 + mi) * 16 + rsel;                                 \
        dst[mi][0] = *(const half8*)&(AH)[r * 64 + ((gsel ^ (r & 7)) << 3)];       \
        dst[mi][1] = *(const half8*)&(AH)[r * 64 + (((4 + gsel) ^ (r & 7)) << 3)]; \
    }
#define READ_B(dst, BH, NH)                                                        \
    _Pragma("unroll") for (int ni = 0; ni < 2; ++ni) {                             \
        const int rn = (wc & 1) * 64 + ((NH) * 2 + ni) * 16 + rsel;                \
        dst[ni][0] = *(const half8*)&(BH)[rn * 64 + ((gsel ^ (rn & 7)) << 3)];     \
        dst[ni][1] = *(const half8*)&(BH)[rn * 64 + (((4 + gsel) ^ (rn & 7)) << 3)]; \
    }
#define MFMA_Q(MH, NH, A_, B_)                                                     \
    _Pragma("unroll") for (int mi = 0; mi < 4; ++mi)                               \
    _Pragma("unroll") for (int ni = 0; ni < 2; ++ni) {                             \
        acc[(MH) * 4 + mi][(NH) * 2 + ni] = __builtin_amdgcn_mfma_f32_16x16x32_f16( \
            A_[mi][0], B_[ni][0], acc[(MH) * 4 + mi][(NH) * 2 + ni], 0, 0, 0);     \
        acc[(MH) * 4 + mi][(NH) * 2 + ni] = __builtin_amdgcn_mfma_f32_16x16x32_f16( \
            A_[mi][1], B_[ni][1], acc[(MH) * 4 + mi][(NH) * 2 + ni], 0, 0, 0);     \
    }
#define SB0 __builtin_amdgcn_sched_barrier(0)

    half8 a_lo[4][2], a_hi[4][2], b_lo[2][2], b_hi[2][2];

    // prologue: stage tile 0, drain, rendezvous
    STAGE(0, 0);
    asm volatile("s_waitcnt vmcnt(0)" ::: "memory");
    __builtin_amdgcn_s_barrier();
    SB0;

#pragma unroll 1
    for (int t = 0; t < NT; ++t) {
        const int buf = t & 1;
        if (t + 1 < NT) { STAGE(buf ^ 1, t + 1); }
        const _Float16* Ah = lds + buf * 32768 + wr * 8192;
        const _Float16* Bh = lds + buf * 32768 + 16384 + (wc >> 1) * 8192;
        // reads in pinned FIFO order: 12 (a_lo+b_lo) | 8 (a_hi) | 4 (b_hi)
        READ_A(a_lo, Ah, 0);
        READ_B(b_lo, Bh, 0);
        SB0;
        READ_A(a_hi, Ah, 1);
        SB0;
        READ_B(b_hi, Bh, 1);
        // Q00 needs first 12 reads; 12 still in flight under its MFMAs
        asm volatile("s_waitcnt lgkmcnt(12)" ::: "memory");
        SB0;
        MFMA_Q(0, 0, a_lo, b_lo);
        // Q10 needs a_hi (reads 13..20); b_hi's 4 may still be in flight
        asm volatile("s_waitcnt lgkmcnt(4)" ::: "memory");
        SB0;
        MFMA_Q(1, 0, a_hi, b_lo);
        asm volatile("s_waitcnt lgkmcnt(0)" ::: "memory");
        SB0;
        MFMA_Q(0, 1, a_lo, b_hi);
        MFMA_Q(1, 1, a_hi, b_hi);
        // own stage loads (issued a full tile ago) must land before rendezvous
        asm volatile("s_waitcnt vmcnt(0)" ::: "memory");
        __builtin_amdgcn_s_barrier();
        SB0;
    }
#undef STAGE
#undef READ_A
#undef READ_B
#undef MFMA_Q
#undef SB0
}

__device__ __forceinline__ void zero_acc8(floatx4 acc[8][4]) {
    const floatx4 z = {0.f, 0.f, 0.f, 0.f};
#pragma unroll
    for (int m = 0; m < 8; ++m)
#pragma unroll
        for (int n = 0; n < 4; ++n) acc[m][n] = z;
}

// ---------------- kernels ----------------

// merged prep: blocks [0,16384) build X fp16 [16384][1024] from concat;
// blocks [16384,20480) convert Wq,Wk,Wv,Wf fp32 -> Wh fp16 [4][1024][1024]
__global__ __launch_bounds__(256) void prep_kernel(const float* e1, const float* e2,
                                                   const float* e3, const float* Wq,
                                                   const float* Wk, const float* Wv,
                                                   const float* Wf, _Float16* X,
                                                   _Float16* Wdst) {
    const int bid = blockIdx.x;
    if (bid < 16384) {
        long i = ((long)bid * 256 + threadIdx.x) * 4;  // < 16384*1024
        int m = (int)(i >> 10);
        int c = (int)(i & 1023);
        const float* src;
        if (c < 256)      src = e1 + (long)m * 256 + c;
        else if (c < 512) src = e2 + (long)m * 256 + (c - 256);
        else              src = e3 + (long)m * 512 + (c - 512);
        float4 f = *(const float4*)src;
        half4v h;
        h[0] = (_Float16)f.x; h[1] = (_Float16)f.y;
        h[2] = (_Float16)f.z; h[3] = (_Float16)f.w;
        *(half4v*)&X[i] = h;
    } else {
        long i = ((long)(bid - 16384) * 256 + threadIdx.x) * 4;  // < 4*1048576
        int which = (int)(i >> 20);
        long off = i & 1048575;
        const float* w = which == 0 ? Wq : which == 1 ? Wk : which == 2 ? Wv : Wf;
        float4 f = *(const float4*)(w + off);
        half4v h;
        h[0] = (_Float16)f.x; h[1] = (_Float16)f.y;
        h[2] = (_Float16)f.z; h[3] = (_Float16)f.w;
        *(half4v*)&Wdst[i] = h;
    }
}

// QKV projection: z=0 -> q, z=1 -> k (row-major [16384][1024]),
// z=2 -> v written TRANSPOSED as vT [1024][16384] via LDS transpose
// (direct scatter was 8B/lane at 32KB stride -> write amplification).
__global__ __launch_bounds__(512, 2) void qkv_kernel(const _Float16* X, const _Float16* W,
                                                     const float* bq, const float* bk,
                                                     const float* bv, _Float16* q,
                                                     _Float16* k, _Float16* vT) {
    extern __shared__ _Float16 lds[];
    const int m0 = blockIdx.x * 256;
    const int n0 = blockIdx.y * 256;
    const int z  = blockIdx.z;
    floatx4 acc[8][4];
    zero_acc8(acc);
    gemm256_core(X + (long)m0 * 1024, 1024,
                 W + (long)z * 1048576 + (long)n0 * 1024, 1024, 1024, acc, lds);

    const float* bias = (z == 0) ? bq : (z == 1) ? bk : bv;
    const int lane = threadIdx.x & 63;
    const int w = threadIdx.x >> 6;
    const int wr = w >> 2, wc = w & 3;
    const int rsel = lane & 15, gsel = lane >> 4;

    if (z == 2) {
        // ---- bias + fp16 cvt into LDS [c][r], XOR-swizzled r to spread banks
        const int rb = wr * 128 + gsel * 4;   // + mI*16 (+j)
        const int cb = wc * 64 + rsel;        // + nI*16
#pragma unroll
        for (int mI = 0; mI < 8; ++mI) {
#pragma unroll
            for (int nI = 0; nI < 4; ++nI) {
                const int c = cb + nI * 16;
                const int r = rb + mI * 16;
                const float bb = bias[n0 + c];
                half4v vv;
#pragma unroll
                for (int j = 0; j < 4; ++j) vv[j] = (_Float16)(acc[mI][nI][j] + bb);
                *(half4v*)&lds[c * 256 + (r ^ ((c & 7) << 3))] = vv;
            }
        }
        __syncthreads();
        // ---- write vT rows: 256 cols x 32 chunks of 16B, contiguous in m
#pragma unroll
        for (int it = 0; it < 16; ++it) {
            const int idx = it * 512 + threadIdx.x;  // 0..8191
            const int c = idx >> 5;                  // 0..255
            const int mc = idx & 31;                 // 16B chunk
            half8 v = *(const half8*)&lds[c * 256 + ((mc * 8) ^ ((c & 7) << 3))];
            *(half8*)&vT[(long)(n0 + c) * 16384 + m0 + mc * 8] = v;
        }
    } else {
        _Float16* dst = (z == 0) ? q : k;
        const int r0 = m0 + wr * 128 + gsel * 4;
        const int c0 = n0 + wc * 64 + rsel;
#pragma unroll
        for (int mI = 0; mI < 8; ++mI) {
#pragma unroll
            for (int nI = 0; nI < 4; ++nI) {
                const int r = r0 + mI * 16;
                const int c = c0 + nI * 16;
                const float bb = bias[c];
#pragma unroll
                for (int j = 0; j < 4; ++j)
                    dst[(long)(r + j) * 1024 + c] = (_Float16)(acc[mI][nI][j] + bb);
            }
        }
    }
}

// scores[b] = q[b] @ k[b]^T  (fp32 out, chunk-local batch index bz)
__global__ __launch_bounds__(512, 2) void scores_kernel(const _Float16* qh,
                                                        const _Float16* kh, float* scores,
                                                        int b0) {
    extern __shared__ _Float16 lds[];
    const int m0 = blockIdx.x * 256;
    const int n0 = blockIdx.y * 256;
    const int bz = blockIdx.z;
    const int batch = b0 + bz;
    float* C = scores + (long)bz * 2048 * 2048;
    floatx4 acc[8][4];
    zero_acc8(acc);
    gemm256_core(qh + ((long)batch * 2048 + m0) * 1024, 1024,
                 kh + ((long)batch * 2048 + n0) * 1024, 1024, 1024, acc, lds);

    const int lane = threadIdx.x & 63;
    const int w = threadIdx.x >> 6;
    const int wr = w >> 2, wc = w & 3;
    const int r0 = m0 + wr * 128 + (lane >> 4) * 4;
    const int c0 = n0 + wc * 64 + (lane & 15);
#pragma unroll
    for (int m = 0; m < 8; ++m) {
#pragma unroll
        for (int n = 0; n < 4; ++n) {
            const int r = r0 + m * 16;
            const int c = c0 + n * 16;
#pragma unroll
            for (int j = 0; j < 4; ++j)
                C[(long)(r + j) * 2048 + c] = acc[m][n][j];
        }
    }
}

// row softmax over 2048 fp32 scores -> fp16 probs. one block per row.
__global__ __launch_bounds__(256) void softmax_kernel(const float* scores,
                                                      _Float16* probs, int b0) {
    const int row = blockIdx.x;
    const int bz  = blockIdx.y;
    const float* s = scores + ((long)bz * 2048 + row) * 2048;
    _Float16* p = probs + ((long)(b0 + bz) * 2048 + row) * 2048;
    const int t = threadIdx.x;

    float4 x0 = ((const float4*)s)[t * 2];
    float4 x1 = ((const float4*)s)[t * 2 + 1];
    float v[8] = {x0.x, x0.y, x0.z, x0.w, x1.x, x1.y, x1.z, x1.w};

    float mx = v[0];
#pragma unroll
    for (int j = 1; j < 8; ++j) mx = fmaxf(mx, v[j]);
#pragma unroll
    for (int d = 1; d < 64; d <<= 1) mx = fmaxf(mx, __shfl_xor(mx, d));
    __shared__ float smax[4];
    __shared__ float ssum[4];
    if ((t & 63) == 0) smax[t >> 6] = mx;
    __syncthreads();
    mx = fmaxf(fmaxf(smax[0], smax[1]), fmaxf(smax[2], smax[3]));

    float e[8];
    float sum = 0.f;
#pragma unroll
    for (int j = 0; j < 8; ++j) {
        e[j] = __expf(v[j] - mx);
        sum += e[j];
    }
#pragma unroll
    for (int d = 1; d < 64; d <<= 1) sum += __shfl_xor(sum, d);
    if ((t & 63) == 0) ssum[t >> 6] = sum;
    __syncthreads();
    sum = ssum[0] + ssum[1] + ssum[2] + ssum[3];
    const float inv = 1.0f / sum;

    half8 o;
#pragma unroll
    for (int j = 0; j < 8; ++j) o[j] = (_Float16)(e[j] * inv);
    *(half8*)&p[t * 8] = o;
}

// weighted[b] = probs[b] @ v[b] via vT (gemm_bt form). fp16 out [16384][1024].
__global__ __launch_bounds__(512, 2) void pv_kernel(const _Float16* probs,
                                                    const _Float16* vT, _Float16* wt) {
    extern __shared__ _Float16 lds[];
    const int m0 = blockIdx.x * 256;
    const int n0 = blockIdx.y * 256;
    const int batch = blockIdx.z;
    floatx4 acc[8][4];
    zero_acc8(acc);
    gemm256_core(probs + ((long)batch * 2048 + m0) * 2048, 2048,
                 vT + (long)n0 * 16384 + (long)batch * 2048, 16384, 2048, acc, lds);

    const int lane = threadIdx.x & 63;
    const int w = threadIdx.x >> 6;
    const int wr = w >> 2, wc = w & 3;
    const int r0 = wr * 128 + (lane >> 4) * 4;
    const int c0 = n0 + wc * 64 + (lane & 15);
#pragma unroll
    for (int m = 0; m < 8; ++m) {
#pragma unroll
        for (int n = 0; n < 4; ++n) {
            const int r = r0 + m * 16;
            const int c = c0 + n * 16;
#pragma unroll
            for (int j = 0; j < 4; ++j)
                wt[((long)batch * 2048 + m0 + r + j) * 1024 + c] =
                    (_Float16)acc[m][n][j];
        }
    }
}

// out = leakyrelu(weighted @ Wf^T + bf), fp32 out.
__global__ __launch_bounds__(512, 2) void out_kernel(const _Float16* wt, const _Float16* Wf,
                                                     const float* bf_, float* out) {
    extern __shared__ _Float16 lds[];
    const int m0 = blockIdx.x * 256;
    const int n0 = blockIdx.y * 256;
    floatx4 acc[8][4];
    zero_acc8(acc);
    gemm256_core(wt + (long)m0 * 1024, 1024, Wf + (long)n0 * 1024, 1024, 1024, acc, lds);

    const int lane = threadIdx.x & 63;
    const int w = threadIdx.x >> 6;
    const int wr = w >> 2, wc = w & 3;
    const int r0 = m0 + wr * 128 + (lane >> 4) * 4;
    const int c0 = n0 + wc * 64 + (lane & 15);
#pragma unroll
    for (int m = 0; m < 8; ++m) {
#pragma unroll
        for (int n = 0; n < 4; ++n) {
            const int r = r0 + m * 16;
            const int c = c0 + n * 16;
            const float bb = bf_[c];
#pragma unroll
            for (int j = 0; j < 4; ++j) {
                float y = acc[m][n][j] + bb;
                y = (y >= 0.f) ? y : 0.2f * y;
                out[(long)(r + j) * 1024 + c] = y;
            }
        }
    }
}

// ---------------- launcher ----------------
extern "C" void kernel_launch(void* const* d_in, const int* in_sizes, int n_in,
                              void* d_out, int out_size, void* d_ws, size_t ws_size,
                              hipStream_t stream) {
    const float* e1 = (const float*)d_in[0];
    const float* e2 = (const float*)d_in[1];
    const float* e3 = (const float*)d_in[2];
    const float* Wq = (const float*)d_in[3];
    const float* bq = (const float*)d_in[4];
    const float* Wk = (const float*)d_in[5];
    const float* bk = (const float*)d_in[6];
    const float* Wv = (const float*)d_in[7];
    const float* bv = (const float*)d_in[8];
    const float* Wf = (const float*)d_in[9];
    const float* bf_ = (const float*)d_in[10];
    float* out = (float*)d_out;

    // raise dynamic-LDS cap to 128 KiB (idempotent; not a stream op)
    const int LDS_BYTES = 131072;
    (void)hipFuncSetAttribute((const void*)qkv_kernel,
                              hipFuncAttributeMaxDynamicSharedMemorySize, LDS_BYTES);
    (void)hipFuncSetAttribute((const void*)scores_kernel,
                              hipFuncAttributeMaxDynamicSharedMemorySize, LDS_BYTES);
    (void)hipFuncSetAttribute((const void*)pv_kernel,
                              hipFuncAttributeMaxDynamicSharedMemorySize, LDS_BYTES);
    (void)hipFuncSetAttribute((const void*)out_kernel,
                              hipFuncAttributeMaxDynamicSharedMemorySize, LDS_BYTES);

    char* ws = (char*)d_ws;
    const size_t MB = 1024 * 1024;
    _Float16* Xh    = (_Float16*)(ws + 0);        // 32 MiB
    _Float16* Wh    = (_Float16*)(ws + 32 * MB);  // 8 MiB [4][1024][1024]
    _Float16* qh    = (_Float16*)(ws + 40 * MB);  // 32 MiB
    _Float16* kh    = (_Float16*)(ws + 72 * MB);  // 32 MiB
    _Float16* vT    = (_Float16*)(ws + 104 * MB); // 32 MiB [1024][16384]
    _Float16* wt    = (_Float16*)(ws + 136 * MB); // 32 MiB
    _Float16* probs = (_Float16*)(ws + 168 * MB); // 64 MiB [8][2048][2048]
    float* scores   = (float*)(ws + 232 * MB);    // NB * 16 MiB scratch

    long nb_max = ((long)ws_size - 232 * (long)MB) / (16 * (long)MB);
    int NB = (int)(nb_max < 1 ? 1 : (nb_max > 8 ? 8 : nb_max));

    prep_kernel<<<20480, 256, 0, stream>>>(e1, e2, e3, Wq, Wk, Wv, Wf, Xh, Wh);
    qkv_kernel<<<dim3(64, 4, 3), 512, LDS_BYTES, stream>>>(Xh, Wh, bq, bk, bv, qh, kh, vT);
    for (int b0 = 0; b0 < 8; b0 += NB) {
        int nb = 8 - b0 < NB ? 8 - b0 : NB;
        scores_kernel<<<dim3(8, 8, nb), 512, LDS_BYTES, stream>>>(qh, kh, scores, b0);
        softmax_kernel<<<dim3(2048, nb), 256, 0, stream>>>(scores, probs, b0);
    }
    pv_kernel<<<dim3(8, 4, 8), 512, LDS_BYTES, stream>>>(probs, vT, wt);
    out_kernel<<<dim3(64, 4), 512, LDS_BYTES, stream>>>(wt, Wh + 3 * 1048576, bf_, out);
}